// Round 6
// baseline (847.415 us; speedup 1.0000x reference)
//
#include <hip/hip_runtime.h>
#include <math.h>
#include <float.h>

#define DDIM 1024   // D
#define PDIM 32     // pattern_dim
#define NPAT 256    // n_patterns
#define TOPK 4
#define BLOCK 256
#define GT   16     // tokens per tile
#define DCH  256    // d-chunk per block
#define NCH  4      // d-chunks (DDIM/DCH)
#define JMAX 8      // tile-slots in grid y (stride loop covers larger n)

// ---------------------------------------------------------------------------
// K0: routing — per token: h = x@W^T, sim = h@K^T, top-4 (tie->lower idx),
// softmax weights. (verbatim-verified R1..R5)
__global__ __launch_bounds__(BLOCK) void route_kernel(
    const float* __restrict__ x,
    const float* __restrict__ hasher_w,   // [PDIM, DDIM]
    const float* __restrict__ keys,       // [NPAT, PDIM]
    int*   __restrict__ tki,              // [ntok, TOPK]
    float* __restrict__ tkw,              // [ntok, TOPK]
    int*   __restrict__ cnt)              // [NPAT]
{
    __shared__ float4 x4_s[DDIM / 4];
    __shared__ float4 h4_s[PDIM / 4];
    __shared__ float  wk_s[TOPK];
    __shared__ int    idx_s[TOPK];
    __shared__ float  wred_v[4];
    __shared__ int    wred_i[4];

    float* x_s = (float*)x4_s;
    float* h_s = (float*)h4_s;

    const int t   = blockIdx.x;
    const int tid = threadIdx.x;

    x4_s[tid] = ((const float4*)(x + (size_t)t * DDIM))[tid];
    __syncthreads();

    {   // h[p], 8 lanes per p
        const int p   = tid >> 3;
        const int seg = tid & 7;
        const float4* wrow = (const float4*)(hasher_w + p * DDIM + seg * 128);
        const float4* xs   = (const float4*)(x_s + seg * 128);
        float acc = 0.f;
        #pragma unroll
        for (int i = 0; i < 32; ++i) {
            float4 w4 = wrow[i];
            float4 a4 = xs[i];
            acc = fmaf(w4.x, a4.x, acc);
            acc = fmaf(w4.y, a4.y, acc);
            acc = fmaf(w4.z, a4.z, acc);
            acc = fmaf(w4.w, a4.w, acc);
        }
        acc += __shfl_down(acc, 4, 8);
        acc += __shfl_down(acc, 2, 8);
        acc += __shfl_down(acc, 1, 8);
        if (seg == 0) h_s[p] = acc;
    }
    __syncthreads();

    float myv;
    {   // sim[n], one thread per pattern
        const float4* krow = (const float4*)(keys + tid * PDIM);
        float acc = 0.f;
        #pragma unroll
        for (int i = 0; i < 8; ++i) {
            float4 k4 = krow[i];
            float4 hh = h4_s[i];
            acc = fmaf(k4.x, hh.x, acc);
            acc = fmaf(k4.y, hh.y, acc);
            acc = fmaf(k4.z, hh.z, acc);
            acc = fmaf(k4.w, hh.w, acc);
        }
        myv = acc;
    }

    for (int r = 0; r < TOPK; ++r) {
        float v = myv;
        int   i = tid;
        #pragma unroll
        for (int off = 32; off > 0; off >>= 1) {
            float ov = __shfl_xor(v, off, 64);
            int   oi = __shfl_xor(i, off, 64);
            if (ov > v || (ov == v && oi < i)) { v = ov; i = oi; }
        }
        const int w = tid >> 6;
        if ((tid & 63) == 0) { wred_v[w] = v; wred_i[w] = i; }
        __syncthreads();
        if (tid == 0) {
            float bv = wred_v[0]; int bi = wred_i[0];
            #pragma unroll
            for (int j = 1; j < 4; ++j) {
                if (wred_v[j] > bv || (wred_v[j] == bv && wred_i[j] < bi)) {
                    bv = wred_v[j]; bi = wred_i[j];
                }
            }
            idx_s[r] = bi;
            wk_s[r]  = bv;
        }
        __syncthreads();
        if (tid == idx_s[r]) myv = -FLT_MAX;
    }

    if (tid == 0) {
        float m = wk_s[0];
        #pragma unroll
        for (int j = 1; j < TOPK; ++j) m = fmaxf(m, wk_s[j]);
        float s = 0.f, e[TOPK];
        #pragma unroll
        for (int j = 0; j < TOPK; ++j) { e[j] = expf(wk_s[j] - m); s += e[j]; }
        #pragma unroll
        for (int j = 0; j < TOPK; ++j) {
            const float wj = e[j] / s;
            tki[t * TOPK + j] = idx_s[j];
            tkw[t * TOPK + j] = wj;
            atomicAdd(&cnt[idx_s[j]], 1);
        }
    }
}

// ---------------------------------------------------------------------------
// K1: single-block scan + CSR fill (verbatim-verified R4/R5)
__global__ __launch_bounds__(NPAT) void scanfill_kernel(
    const int* __restrict__ cnt,
    const int* __restrict__ tki, const float* __restrict__ tkw,
    const float* __restrict__ scale_p,
    int* __restrict__ offs,
    int* __restrict__ etok, float* __restrict__ ew, int* __restrict__ slotof,
    int nent)
{
    __shared__ int s[NPAT];
    __shared__ int cur[NPAT];
    const int tid = threadIdx.x;

    const int v = cnt[tid];
    s[tid] = v;
    __syncthreads();
    for (int off = 1; off < NPAT; off <<= 1) {
        int t = 0;
        if (tid >= off) t = s[tid - off];
        __syncthreads();
        s[tid] += t;
        __syncthreads();
    }
    const int incl = s[tid];
    offs[tid + 1] = incl;
    if (tid == 0) offs[0] = 0;
    cur[tid] = incl - v;
    __syncthreads();

    const float sc = scale_p[0];
    for (int e = tid; e < nent; e += NPAT) {
        const int p = tki[e];
        const int slot = atomicAdd(&cur[p], 1);
        etok[slot] = e >> 2;
        ew[slot]   = tkw[e] * sc;
        slotof[e]  = slot;
    }
}

// ---------------------------------------------------------------------------
// K2: down-projection. R6: ONE 16-token tile per block (grid y = tile slot,
// stride loop for large n); vd streamed straight from global (zero-redundancy
// 1KB/instr wave coverage, L2/L3-resident) — LDS only for x tile + reduction.
// 21 KB LDS, 4 blocks/CU, ~2250 active blocks -> block-level latency churn.
__global__ __launch_bounds__(BLOCK, 4) void proj_kernel(
    const float* __restrict__ x,
    const float* __restrict__ vd,          // [NPAT, DDIM, PDIM]
    const int* __restrict__ offs,
    const int* __restrict__ etok,
    float* __restrict__ part,              // [NCH][nent+1][PDIM]
    int nent)
{
    __shared__ float x_s[GT * DCH];        // 16 KB
    __shared__ float red[4][8][36];        // 4.6 KB

    const int p   = blockIdx.x >> 2;
    const int c   = blockIdx.x & 3;
    const int tid = threadIdx.x;
    const int off0 = offs[p];
    const int n    = offs[p + 1] - off0;

    const float* vdp = vd + (size_t)p * DDIM * PDIM + (size_t)c * DCH * PDIM;
    float* partc = part + (size_t)c * (size_t)(nent + 1) * PDIM;

    const int pp4 = tid & 7;      // pp quad
    const int seg = tid >> 3;     // 0..31, 8 d's each

    for (int t0 = blockIdx.y * GT; t0 < n; t0 += gridDim.y * GT) {
        const int gv = min(GT, n - t0);

        // stage x tile chunk (16 rows x 256 floats); token via broadcast etok
        #pragma unroll
        for (int k = 0; k < 4; ++k) {
            const int q  = k * 256 + tid;      // float4 index
            const int g  = q >> 6, fi = q & 63;
            const int tk = etok[off0 + t0 + (g < gv ? g : 0)];
            ((float4*)x_s)[q] =
                *(const float4*)(x + (size_t)tk * DDIM + c * DCH + fi * 4);
        }
        __syncthreads();

        float4 acc[GT];
        #pragma unroll
        for (int g = 0; g < GT; ++g) acc[g] = make_float4(0.f, 0.f, 0.f, 0.f);

        #pragma unroll
        for (int i4 = 0; i4 < 2; ++i4) {
            const int d0 = seg * 8 + i4 * 4;
            const float* b2 = vdp + (size_t)d0 * PDIM + pp4 * 4;
            const float4 v0 = *(const float4*)(b2);
            const float4 v1 = *(const float4*)(b2 + PDIM);
            const float4 v2 = *(const float4*)(b2 + 2 * PDIM);
            const float4 v3 = *(const float4*)(b2 + 3 * PDIM);
            #pragma unroll
            for (int g = 0; g < GT; ++g) {
                const float4 xg = *(const float4*)&x_s[g * DCH + d0];
                acc[g].x = fmaf(xg.x, v0.x, acc[g].x);
                acc[g].y = fmaf(xg.x, v0.y, acc[g].y);
                acc[g].z = fmaf(xg.x, v0.z, acc[g].z);
                acc[g].w = fmaf(xg.x, v0.w, acc[g].w);
                acc[g].x = fmaf(xg.y, v1.x, acc[g].x);
                acc[g].y = fmaf(xg.y, v1.y, acc[g].y);
                acc[g].z = fmaf(xg.y, v1.z, acc[g].z);
                acc[g].w = fmaf(xg.y, v1.w, acc[g].w);
                acc[g].x = fmaf(xg.z, v2.x, acc[g].x);
                acc[g].y = fmaf(xg.z, v2.y, acc[g].y);
                acc[g].z = fmaf(xg.z, v2.z, acc[g].z);
                acc[g].w = fmaf(xg.z, v2.w, acc[g].w);
                acc[g].x = fmaf(xg.w, v3.x, acc[g].x);
                acc[g].y = fmaf(xg.w, v3.y, acc[g].y);
                acc[g].z = fmaf(xg.w, v3.z, acc[g].z);
                acc[g].w = fmaf(xg.w, v3.w, acc[g].w);
            }
        }

        // in-wave reduce over 8 segs (lane bits 3..5)
        #pragma unroll
        for (int g = 0; g < GT; ++g) {
            #pragma unroll
            for (int off = 8; off <= 32; off <<= 1) {
                acc[g].x += __shfl_xor(acc[g].x, off, 64);
                acc[g].y += __shfl_xor(acc[g].y, off, 64);
                acc[g].z += __shfl_xor(acc[g].z, off, 64);
                acc[g].w += __shfl_xor(acc[g].w, off, 64);
            }
        }
        const int wv = tid >> 6;
        if ((tid & 0x38) == 0) {
            #pragma unroll
            for (int g = 0; g < GT; ++g)
                *(float4*)&red[wv][pp4][g * 4] = acc[g];
        }
        __syncthreads();

        // cross-wave reduce + write partial proj (computed slots, coalesced)
        #pragma unroll
        for (int r = 0; r < 2; ++r) {
            const int idx = tid + r * BLOCK;       // 0..511
            const int g = idx >> 5, pp = idx & 31;
            const int q = pp >> 2, cmp = g * 4 + (pp & 3);
            const float s = red[0][q][cmp] + red[1][q][cmp]
                          + red[2][q][cmp] + red[3][q][cmp];
            const int slot = (g < gv) ? (off0 + t0 + g) : nent;
            partc[(size_t)slot * PDIM + pp] = s;
        }
        __syncthreads();   // only matters if the stride loop continues
    }
}

// ---------------------------------------------------------------------------
// K3: up-projection. R6: one tile per block (grid y), vu streamed from global
// (coalesced 1KB/instr, 4x wave reuse via L1), LDS only projT (~3 KB).
template <int MODE>
__global__ __launch_bounds__(BLOCK, 8) void up_kernel(
    const float* __restrict__ vu,          // [NPAT, PDIM, DDIM]
    const int* __restrict__ offs,
    const int* __restrict__ etok,
    const float* __restrict__ ew,
    const float* __restrict__ part,        // [NCH][nent+1][PDIM]
    float* __restrict__ dst,               // contrib (MODE 0) or out (MODE 1)
    int nent)
{
    __shared__ float projT[PDIM][20];      // [pp][g], pad 20

    const int p   = blockIdx.x >> 2;
    const int c   = blockIdx.x & 3;
    const int tid = threadIdx.x;
    const int off0 = offs[p];
    const int n    = offs[p + 1] - off0;

    const size_t PS = (size_t)(nent + 1) * PDIM;   // part slice stride
    const float* vup = vu + (size_t)p * PDIM * DDIM + (size_t)c * DCH;

    const int gq   = tid >> 6;    // wave -> 4 tokens
    const int lane = tid & 63;    // -> 4 d's

    for (int t0 = blockIdx.y * GT; t0 < n; t0 += gridDim.y * GT) {
        const int gv = min(GT, n - t0);

        // proj = silu(sum of 4 d-chunk partials) * weight  (slots computed)
        #pragma unroll
        for (int r = 0; r < 2; ++r) {
            const int idx = tid + r * BLOCK;
            const int g = idx >> 5, pp = idx & 31;
            const bool valid = (g < gv);
            const int slot = valid ? (off0 + t0 + g) : nent;
            const float wgt = valid ? ew[off0 + t0 + g] : 0.f;
            const size_t row = (size_t)slot * PDIM + pp;
            const float s = part[row] + part[PS + row]
                          + part[2 * PS + row] + part[3 * PS + row];
            const float pj = s / (1.f + expf(-s));
            projT[pp][g] = pj * wgt;
        }
        __syncthreads();

        float4 o0 = make_float4(0.f, 0.f, 0.f, 0.f);
        float4 o1 = o0, o2 = o0, o3 = o0;
        #pragma unroll
        for (int pp = 0; pp < PDIM; ++pp) {
            const float4 pj4 = *(const float4*)&projT[pp][gq * 4];
            const float4 vu4 = *(const float4*)(vup + (size_t)pp * DDIM + lane * 4);
            o0.x = fmaf(pj4.x, vu4.x, o0.x); o0.y = fmaf(pj4.x, vu4.y, o0.y);
            o0.z = fmaf(pj4.x, vu4.z, o0.z); o0.w = fmaf(pj4.x, vu4.w, o0.w);
            o1.x = fmaf(pj4.y, vu4.x, o1.x); o1.y = fmaf(pj4.y, vu4.y, o1.y);
            o1.z = fmaf(pj4.y, vu4.z, o1.z); o1.w = fmaf(pj4.y, vu4.w, o1.w);
            o2.x = fmaf(pj4.z, vu4.x, o2.x); o2.y = fmaf(pj4.z, vu4.y, o2.y);
            o2.z = fmaf(pj4.z, vu4.z, o2.z); o2.w = fmaf(pj4.z, vu4.w, o2.w);
            o3.x = fmaf(pj4.w, vu4.x, o3.x); o3.y = fmaf(pj4.w, vu4.y, o3.y);
            o3.z = fmaf(pj4.w, vu4.z, o3.z); o3.w = fmaf(pj4.w, vu4.w, o3.w);
        }

        float4 ov[4] = {o0, o1, o2, o3};
        if (MODE == 0) {
            #pragma unroll
            for (int j = 0; j < 4; ++j) {
                const int g = gq * 4 + j;
                const int slot = (g < gv) ? (off0 + t0 + g) : nent;
                *(float4*)(dst + (size_t)slot * DDIM + c * DCH + lane * 4) = ov[j];
            }
        } else {
            #pragma unroll
            for (int j = 0; j < 4; ++j) {
                const int g = gq * 4 + j;
                if (g < gv) {
                    const int tok = etok[off0 + t0 + g];
                    float* op = dst + (size_t)tok * DDIM + c * DCH + lane * 4;
                    atomicAdd(op + 0, ov[j].x);
                    atomicAdd(op + 1, ov[j].y);
                    atomicAdd(op + 2, ov[j].z);
                    atomicAdd(op + 3, ov[j].w);
                }
            }
        }
        __syncthreads();   // only matters if the stride loop continues
    }
}

// ---------------------------------------------------------------------------
// K4: out[t] = x[t] + sum_k contrib[slotof[t][k]]  (verbatim-verified)
__global__ __launch_bounds__(BLOCK) void combine_kernel(
    const float* __restrict__ x, const float* __restrict__ contrib,
    const int* __restrict__ slotof, float* __restrict__ out)
{
    __shared__ int sl[TOPK];
    const int t = blockIdx.x, tid = threadIdx.x;
    if (tid < TOPK) sl[tid] = slotof[t * TOPK + tid];
    __syncthreads();
    float4 r = ((const float4*)(x + (size_t)t * DDIM))[tid];
    #pragma unroll
    for (int k = 0; k < TOPK; ++k) {
        const float4 cv = ((const float4*)(contrib + (size_t)sl[k] * DDIM))[tid];
        r.x += cv.x; r.y += cv.y; r.z += cv.z; r.w += cv.w;
    }
    ((float4*)(out + (size_t)t * DDIM))[tid] = r;
}

// ---------------------------------------------------------------------------
extern "C" void kernel_launch(void* const* d_in, const int* in_sizes, int n_in,
                              void* d_out, int out_size, void* d_ws, size_t ws_size,
                              hipStream_t stream) {
    const float* x        = (const float*)d_in[0];
    const float* hasher_w = (const float*)d_in[1];
    const float* keys     = (const float*)d_in[2];
    const float* vd       = (const float*)d_in[3];
    const float* vu       = (const float*)d_in[4];
    const float* scale    = (const float*)d_in[5];
    float* out = (float*)d_out;

    const int ntok = in_sizes[0] / DDIM;        // B*T
    const int nent = ntok * TOPK;

    // workspace layout
    char* w = (char*)d_ws;
    const size_t o_cnt  = 0;                                      // 256 int
    const size_t o_offs = 1024;                                   // 257 int
    const size_t o_tki  = 2560;                                   // nent int
    const size_t o_tkw  = o_tki  + (size_t)nent * 4;
    const size_t o_etok = o_tkw  + (size_t)nent * 4;
    const size_t o_ew   = o_etok + (size_t)nent * 4;
    const size_t o_slot = o_ew   + (size_t)nent * 4;
    const size_t o_part = (o_slot + (size_t)nent * 4 + 255) & ~(size_t)255;
    const size_t partsz = (size_t)NCH * (size_t)(nent + 1) * PDIM * 4;
    const size_t o_ctb  = (o_part + partsz + 255) & ~(size_t)255;
    const size_t needPart    = o_ctb;                              // atomic path
    const size_t needContrib = o_ctb + (size_t)(nent + 1) * DDIM * 4;

    int*   cnt    = (int*)(w + o_cnt);
    int*   offs   = (int*)(w + o_offs);
    int*   tki    = (int*)(w + o_tki);
    float* tkw    = (float*)(w + o_tkw);
    int*   etok   = (int*)(w + o_etok);
    float* ew     = (float*)(w + o_ew);
    int*   slotof = (int*)(w + o_slot);
    float* part   = (float*)(w + o_part);
    float* contrib= (float*)(w + o_ctb);

    hipMemsetAsync(cnt, 0, NPAT * sizeof(int), stream);
    hipLaunchKernelGGL(route_kernel, dim3(ntok), dim3(BLOCK), 0, stream,
                       x, hasher_w, keys, tki, tkw, cnt);
    hipLaunchKernelGGL(scanfill_kernel, dim3(1), dim3(NPAT), 0, stream,
                       cnt, tki, tkw, scale, offs, etok, ew, slotof, nent);
    hipLaunchKernelGGL(proj_kernel, dim3(NPAT * NCH, JMAX), dim3(BLOCK), 0, stream,
                       x, vd, offs, etok, part, nent);

    if (ws_size >= needContrib) {
        hipLaunchKernelGGL((up_kernel<0>), dim3(NPAT * NCH, JMAX), dim3(BLOCK),
                           0, stream, vu, offs, etok, ew, part, contrib, nent);
        hipLaunchKernelGGL(combine_kernel, dim3(ntok), dim3(BLOCK), 0, stream,
                           x, contrib, slotof, out);
    } else if (ws_size >= needPart) {
        hipMemcpyAsync(out, x, (size_t)ntok * DDIM * 4, hipMemcpyDeviceToDevice,
                       stream);
        hipLaunchKernelGGL((up_kernel<1>), dim3(NPAT * NCH, JMAX), dim3(BLOCK),
                           0, stream, vu, offs, etok, ew, part, out, nent);
    }
}

// Round 7
// 298.050 us; speedup vs baseline: 2.8432x; 2.8432x over previous
//
#include <hip/hip_runtime.h>
#include <math.h>
#include <float.h>

#define DDIM 1024   // D
#define PDIM 32     // pattern_dim
#define NPAT 256    // n_patterns
#define TOPK 4
#define BLOCK 256
#define GT   16     // tokens per tile
#define DCH  256    // d-chunk per block
#define NCH  4      // d-chunks (DDIM/DCH)
#define TPB  16     // tokens per route block

// ---------------------------------------------------------------------------
// K0 (R7): routing, 16 tokens/block. Thread (t=tid>>4, pp2=tid&15) owns
// h[t][pp2] and h[t][pp2+16] fully in registers (hasher_w streamed once per
// block, L2-hot). Then wave w handles tokens 4w..4w+3: sim vs all 256 keys
// (lane = pattern within 4 chunks of 64), top-4 via butterfly argmax
// (tie -> lower index, matching jax.lax.top_k), softmax, write tki/tkw.
__global__ __launch_bounds__(BLOCK) void route_kernel(
    const float* __restrict__ x,
    const float* __restrict__ hasher_w,   // [PDIM, DDIM]
    const float* __restrict__ keys,       // [NPAT, PDIM]
    int*   __restrict__ tki,              // [ntok, TOPK]
    float* __restrict__ tkw,              // [ntok, TOPK]
    int ntok)
{
    __shared__ float h_s[TPB][36];        // pad 36: 16B-aligned rows, 2-way max

    const int tid  = threadIdx.x;
    const int t    = tid >> 4;            // local token 0..15
    const int pp2  = tid & 15;
    const int tok0 = blockIdx.x * TPB;

    // ---- phase 1: h[t][pp2], h[t][pp2+16]
    {
        const int tok = min(tok0 + t, ntok - 1);
        const float4* xr  = (const float4*)(x + (size_t)tok * DDIM);
        const float4* hwA = (const float4*)(hasher_w + (size_t)pp2 * DDIM);
        const float4* hwB = (const float4*)(hasher_w + (size_t)(pp2 + 16) * DDIM);
        float accA = 0.f, accB = 0.f;
        #pragma unroll 8
        for (int fi = 0; fi < DDIM / 4; ++fi) {
            const float4 x4 = xr[fi];
            const float4 a4 = hwA[fi];
            const float4 b4 = hwB[fi];
            accA = fmaf(x4.x, a4.x, accA); accA = fmaf(x4.y, a4.y, accA);
            accA = fmaf(x4.z, a4.z, accA); accA = fmaf(x4.w, a4.w, accA);
            accB = fmaf(x4.x, b4.x, accB); accB = fmaf(x4.y, b4.y, accB);
            accB = fmaf(x4.z, b4.z, accB); accB = fmaf(x4.w, b4.w, accB);
        }
        h_s[t][pp2]      = accA;
        h_s[t][pp2 + 16] = accB;
    }
    __syncthreads();

    // ---- phase 2: per-wave sim + top4 + softmax for 4 tokens
    const int wv   = tid >> 6;            // wave 0..3
    const int lane = tid & 63;

    for (int j = 0; j < 4; ++j) {
        const int tt  = wv * 4 + j;       // local token
        const int tok = tok0 + tt;
        if (tok >= ntok) break;

        // h row (broadcast LDS reads)
        float4 h4[8];
        #pragma unroll
        for (int i = 0; i < 8; ++i) h4[i] = *(const float4*)&h_s[tt][i * 4];

        // sims for patterns c*64+lane, c=0..3
        float sc0, sc1, sc2, sc3;
        {
            float sv[4];
            #pragma unroll
            for (int c = 0; c < 4; ++c) {
                const float4* kr = (const float4*)(keys + (size_t)(c * 64 + lane) * PDIM);
                float a = 0.f;
                #pragma unroll
                for (int i = 0; i < 8; ++i) {
                    const float4 k4 = kr[i];
                    a = fmaf(k4.x, h4[i].x, a); a = fmaf(k4.y, h4[i].y, a);
                    a = fmaf(k4.z, h4[i].z, a); a = fmaf(k4.w, h4[i].w, a);
                }
                sv[c] = a;
            }
            sc0 = sv[0]; sc1 = sv[1]; sc2 = sv[2]; sc3 = sv[3];
        }

        float wval[TOPK]; int widx[TOPK];
        #pragma unroll
        for (int r = 0; r < TOPK; ++r) {
            // per-lane best chunk (strict > keeps lower c on ties)
            float bv = sc0; int bc = 0;
            if (sc1 > bv) { bv = sc1; bc = 1; }
            if (sc2 > bv) { bv = sc2; bc = 2; }
            if (sc3 > bv) { bv = sc3; bc = 3; }
            int bidx = bc * 64 + lane;
            // wave butterfly argmax, tie -> lower pattern index
            #pragma unroll
            for (int off = 1; off < 64; off <<= 1) {
                const float ov = __shfl_xor(bv, off, 64);
                const int   oi = __shfl_xor(bidx, off, 64);
                if (ov > bv || (ov == bv && oi < bidx)) { bv = ov; bidx = oi; }
            }
            wval[r] = bv; widx[r] = bidx;
            // knock out the winner in its owner lane
            if ((bidx & 63) == lane) {
                const int c = bidx >> 6;
                if (c == 0) sc0 = -FLT_MAX;
                else if (c == 1) sc1 = -FLT_MAX;
                else if (c == 2) sc2 = -FLT_MAX;
                else sc3 = -FLT_MAX;
            }
        }

        if (lane == 0) {
            float m = wval[0];
            #pragma unroll
            for (int k = 1; k < TOPK; ++k) m = fmaxf(m, wval[k]);
            float s = 0.f, e[TOPK];
            #pragma unroll
            for (int k = 0; k < TOPK; ++k) { e[k] = expf(wval[k] - m); s += e[k]; }
            #pragma unroll
            for (int k = 0; k < TOPK; ++k) {
                tki[tok * TOPK + k] = widx[k];
                tkw[tok * TOPK + k] = e[k] / s;
            }
        }
    }
}

// ---------------------------------------------------------------------------
// K1 (R7): count (from tki, in LDS) + scan + CSR fill, single block.
__global__ __launch_bounds__(NPAT) void scanfill_kernel(
    const int* __restrict__ tki, const float* __restrict__ tkw,
    const float* __restrict__ scale_p,
    int* __restrict__ offs,
    int* __restrict__ etok, float* __restrict__ ew, int* __restrict__ slotof,
    int nent)
{
    __shared__ int s[NPAT];
    __shared__ int cur[NPAT];
    const int tid = threadIdx.x;

    cur[tid] = 0;
    __syncthreads();
    for (int e = tid; e < nent; e += NPAT) atomicAdd(&cur[tki[e]], 1);
    __syncthreads();

    const int v = cur[tid];
    s[tid] = v;
    __syncthreads();
    for (int off = 1; off < NPAT; off <<= 1) {
        int t = 0;
        if (tid >= off) t = s[tid - off];
        __syncthreads();
        s[tid] += t;
        __syncthreads();
    }
    const int incl = s[tid];
    offs[tid + 1] = incl;
    if (tid == 0) offs[0] = 0;
    cur[tid] = incl - v;
    __syncthreads();

    const float sc = scale_p[0];
    for (int e = tid; e < nent; e += NPAT) {
        const int p = tki[e];
        const int slot = atomicAdd(&cur[p], 1);
        etok[slot] = e >> 2;
        ew[slot]   = tkw[e] * sc;
        slotof[e]  = slot;
    }
}

// ---------------------------------------------------------------------------
// K2: down-projection, d-split (verbatim from R4's 248 µs best: vd staged in
// LDS, gt/gs arrays, launch_bounds(256,2)).
__global__ __launch_bounds__(BLOCK, 2) void proj_kernel(
    const float* __restrict__ x,
    const float* __restrict__ vd,          // [NPAT, DDIM, PDIM]
    const int* __restrict__ offs,
    const int* __restrict__ etok,
    float* __restrict__ part,              // [NCH][nent+1][PDIM]
    int nent)
{
    __shared__ float vd_s[DCH * PDIM];     // 32 KB
    __shared__ float x_s[GT * DCH];        // 16 KB
    __shared__ float red[4][8][68];        // 8.7 KB
    __shared__ int   gt[GT];
    __shared__ int   gs[GT];

    const int p   = blockIdx.x >> 2;
    const int c   = blockIdx.x & 3;
    const int tid = threadIdx.x;
    const int off0 = offs[p];
    const int n    = offs[p + 1] - off0;
    if (n == 0) return;

    const float* vdp = vd + (size_t)p * DDIM * PDIM + (size_t)c * DCH * PDIM;
    #pragma unroll
    for (int k = 0; k < 8; ++k)
        ((float4*)vd_s)[k * 256 + tid] = ((const float4*)vdp)[k * 256 + tid];
    __syncthreads();

    const int pp4 = tid & 7;
    const int seg = tid >> 3;
    float* partc = part + (size_t)c * (size_t)(nent + 1) * PDIM;

    for (int t0 = 0; t0 < n; t0 += GT) {
        const int gv = min(GT, n - t0);
        if (tid < GT) {
            if (tid < gv) { gt[tid] = etok[off0 + t0 + tid]; gs[tid] = off0 + t0 + tid; }
            else          { gt[tid] = etok[off0];            gs[tid] = nent; }
        }
        __syncthreads();

        #pragma unroll
        for (int k = 0; k < 4; ++k) {
            const int q  = k * 256 + tid;
            const int g  = q >> 6, fi = q & 63;
            ((float4*)x_s)[g * 64 + fi] =
                *(const float4*)(x + (size_t)gt[g] * DDIM + c * DCH + fi * 4);
        }
        __syncthreads();

        float4 acc[GT];
        #pragma unroll
        for (int g = 0; g < GT; ++g) acc[g] = make_float4(0.f, 0.f, 0.f, 0.f);

        #pragma unroll
        for (int i4 = 0; i4 < 2; ++i4) {
            const int d0 = seg * 8 + i4 * 4;
            const float4 v0 = *(const float4*)&vd_s[(d0 + 0) * PDIM + pp4 * 4];
            const float4 v1 = *(const float4*)&vd_s[(d0 + 1) * PDIM + pp4 * 4];
            const float4 v2 = *(const float4*)&vd_s[(d0 + 2) * PDIM + pp4 * 4];
            const float4 v3 = *(const float4*)&vd_s[(d0 + 3) * PDIM + pp4 * 4];
            #pragma unroll
            for (int g = 0; g < GT; ++g) {
                const float4 xg = *(const float4*)&x_s[g * DCH + d0];
                acc[g].x = fmaf(xg.x, v0.x, acc[g].x);
                acc[g].y = fmaf(xg.x, v0.y, acc[g].y);
                acc[g].z = fmaf(xg.x, v0.z, acc[g].z);
                acc[g].w = fmaf(xg.x, v0.w, acc[g].w);
                acc[g].x = fmaf(xg.y, v1.x, acc[g].x);
                acc[g].y = fmaf(xg.y, v1.y, acc[g].y);
                acc[g].z = fmaf(xg.y, v1.z, acc[g].z);
                acc[g].w = fmaf(xg.y, v1.w, acc[g].w);
                acc[g].x = fmaf(xg.z, v2.x, acc[g].x);
                acc[g].y = fmaf(xg.z, v2.y, acc[g].y);
                acc[g].z = fmaf(xg.z, v2.z, acc[g].z);
                acc[g].w = fmaf(xg.z, v2.w, acc[g].w);
                acc[g].x = fmaf(xg.w, v3.x, acc[g].x);
                acc[g].y = fmaf(xg.w, v3.y, acc[g].y);
                acc[g].z = fmaf(xg.w, v3.z, acc[g].z);
                acc[g].w = fmaf(xg.w, v3.w, acc[g].w);
            }
        }

        #pragma unroll
        for (int g = 0; g < GT; ++g) {
            #pragma unroll
            for (int off = 8; off <= 32; off <<= 1) {
                acc[g].x += __shfl_xor(acc[g].x, off, 64);
                acc[g].y += __shfl_xor(acc[g].y, off, 64);
                acc[g].z += __shfl_xor(acc[g].z, off, 64);
                acc[g].w += __shfl_xor(acc[g].w, off, 64);
            }
        }
        const int wv = tid >> 6;
        if ((tid & 0x38) == 0) {
            #pragma unroll
            for (int g = 0; g < GT; ++g)
                *(float4*)&red[wv][pp4][g * 4] = acc[g];
        }
        __syncthreads();

        #pragma unroll
        for (int r = 0; r < 2; ++r) {
            const int idx = tid + r * BLOCK;
            const int g = idx >> 5, pp = idx & 31;
            const int q = pp >> 2, cmp = g * 4 + (pp & 3);
            const float s = red[0][q][cmp] + red[1][q][cmp]
                          + red[2][q][cmp] + red[3][q][cmp];
            partc[(size_t)gs[g] * PDIM + pp] = s;
        }
        __syncthreads();
    }
}

// ---------------------------------------------------------------------------
// K3: up-projection, d-split (verbatim from R4's 248 µs best: vu staged in
// LDS, gt/gw/gs arrays, launch_bounds(256,4)).
template <int MODE>
__global__ __launch_bounds__(BLOCK, 4) void up_kernel(
    const float* __restrict__ vu,          // [NPAT, PDIM, DDIM]
    const int* __restrict__ offs,
    const int* __restrict__ etok,
    const float* __restrict__ ew,
    const float* __restrict__ part,        // [NCH][nent+1][PDIM]
    float* __restrict__ dst,               // contrib (MODE 0) or out (MODE 1)
    int nent)
{
    __shared__ float vu_s[PDIM * DCH];     // 32 KB
    __shared__ float projT[PDIM][20];
    __shared__ int   gt[GT];
    __shared__ float gw[GT];
    __shared__ int   gs[GT];

    const int p   = blockIdx.x >> 2;
    const int c   = blockIdx.x & 3;
    const int tid = threadIdx.x;
    const int off0 = offs[p];
    const int n    = offs[p + 1] - off0;
    if (n == 0) return;

    const size_t PS = (size_t)(nent + 1) * PDIM;

    const float* vup = vu + (size_t)p * PDIM * DDIM + (size_t)c * DCH;
    #pragma unroll
    for (int k = 0; k < 8; ++k) {
        const int q  = k * 256 + tid;
        const int pp = q >> 6, fi = q & 63;
        *(float4*)&vu_s[pp * DCH + fi * 4] =
            *(const float4*)(vup + (size_t)pp * DDIM + fi * 4);
    }
    __syncthreads();

    const int gq   = tid >> 6;
    const int lane = tid & 63;

    for (int t0 = 0; t0 < n; t0 += GT) {
        const int gv = min(GT, n - t0);
        if (tid < GT) {
            if (tid < gv) {
                gt[tid] = etok[off0 + t0 + tid];
                gw[tid] = ew[off0 + t0 + tid];
                gs[tid] = off0 + t0 + tid;
            } else {
                gt[tid] = etok[off0]; gw[tid] = 0.f; gs[tid] = nent;
            }
        }
        __syncthreads();

        #pragma unroll
        for (int r = 0; r < 2; ++r) {
            const int idx = tid + r * BLOCK;
            const int g = idx >> 5, pp = idx & 31;
            const size_t row = (size_t)gs[g] * PDIM + pp;
            const float s = part[row] + part[PS + row]
                          + part[2 * PS + row] + part[3 * PS + row];
            const float pj = s / (1.f + expf(-s));
            projT[pp][g] = pj * gw[g];
        }
        __syncthreads();

        float4 o0 = make_float4(0.f, 0.f, 0.f, 0.f);
        float4 o1 = o0, o2 = o0, o3 = o0;
        #pragma unroll
        for (int pp = 0; pp < PDIM; ++pp) {
            const float4 pj4 = *(const float4*)&projT[pp][gq * 4];
            const float4 vu4 = *(const float4*)&vu_s[pp * DCH + lane * 4];
            o0.x = fmaf(pj4.x, vu4.x, o0.x); o0.y = fmaf(pj4.x, vu4.y, o0.y);
            o0.z = fmaf(pj4.x, vu4.z, o0.z); o0.w = fmaf(pj4.x, vu4.w, o0.w);
            o1.x = fmaf(pj4.y, vu4.x, o1.x); o1.y = fmaf(pj4.y, vu4.y, o1.y);
            o1.z = fmaf(pj4.y, vu4.z, o1.z); o1.w = fmaf(pj4.y, vu4.w, o1.w);
            o2.x = fmaf(pj4.z, vu4.x, o2.x); o2.y = fmaf(pj4.z, vu4.y, o2.y);
            o2.z = fmaf(pj4.z, vu4.z, o2.z); o2.w = fmaf(pj4.z, vu4.w, o2.w);
            o3.x = fmaf(pj4.w, vu4.x, o3.x); o3.y = fmaf(pj4.w, vu4.y, o3.y);
            o3.z = fmaf(pj4.w, vu4.z, o3.z); o3.w = fmaf(pj4.w, vu4.w, o3.w);
        }

        float4 ov[4] = {o0, o1, o2, o3};
        if (MODE == 0) {
            #pragma unroll
            for (int j = 0; j < 4; ++j)
                *(float4*)(dst + (size_t)gs[gq * 4 + j] * DDIM + c * DCH + lane * 4) = ov[j];
        } else {
            #pragma unroll
            for (int j = 0; j < 4; ++j) {
                const int g = gq * 4 + j;
                if (g < gv) {
                    float* op = dst + (size_t)gt[g] * DDIM + c * DCH + lane * 4;
                    atomicAdd(op + 0, ov[j].x);
                    atomicAdd(op + 1, ov[j].y);
                    atomicAdd(op + 2, ov[j].z);
                    atomicAdd(op + 3, ov[j].w);
                }
            }
        }
        __syncthreads();
    }
}

// ---------------------------------------------------------------------------
// K4: out[t] = x[t] + sum_k contrib[slotof[t][k]]  (verbatim-verified)
__global__ __launch_bounds__(BLOCK) void combine_kernel(
    const float* __restrict__ x, const float* __restrict__ contrib,
    const int* __restrict__ slotof, float* __restrict__ out)
{
    __shared__ int sl[TOPK];
    const int t = blockIdx.x, tid = threadIdx.x;
    if (tid < TOPK) sl[tid] = slotof[t * TOPK + tid];
    __syncthreads();
    float4 r = ((const float4*)(x + (size_t)t * DDIM))[tid];
    #pragma unroll
    for (int k = 0; k < TOPK; ++k) {
        const float4 cv = ((const float4*)(contrib + (size_t)sl[k] * DDIM))[tid];
        r.x += cv.x; r.y += cv.y; r.z += cv.z; r.w += cv.w;
    }
    ((float4*)(out + (size_t)t * DDIM))[tid] = r;
}

// ---------------------------------------------------------------------------
extern "C" void kernel_launch(void* const* d_in, const int* in_sizes, int n_in,
                              void* d_out, int out_size, void* d_ws, size_t ws_size,
                              hipStream_t stream) {
    const float* x        = (const float*)d_in[0];
    const float* hasher_w = (const float*)d_in[1];
    const float* keys     = (const float*)d_in[2];
    const float* vd       = (const float*)d_in[3];
    const float* vu       = (const float*)d_in[4];
    const float* scale    = (const float*)d_in[5];
    float* out = (float*)d_out;

    const int ntok = in_sizes[0] / DDIM;        // B*T
    const int nent = ntok * TOPK;

    // workspace layout (R4-compatible; cnt slot retired)
    char* w = (char*)d_ws;
    const size_t o_offs = 1024;                                   // 257 int
    const size_t o_tki  = 2560;                                   // nent int
    const size_t o_tkw  = o_tki  + (size_t)nent * 4;
    const size_t o_etok = o_tkw  + (size_t)nent * 4;
    const size_t o_ew   = o_etok + (size_t)nent * 4;
    const size_t o_slot = o_ew   + (size_t)nent * 4;
    const size_t o_part = (o_slot + (size_t)nent * 4 + 255) & ~(size_t)255;
    const size_t partsz = (size_t)NCH * (size_t)(nent + 1) * PDIM * 4;
    const size_t o_ctb  = (o_part + partsz + 255) & ~(size_t)255;
    const size_t needPart    = o_ctb;                              // atomic path
    const size_t needContrib = o_ctb + (size_t)(nent + 1) * DDIM * 4;

    int*   offs   = (int*)(w + o_offs);
    int*   tki    = (int*)(w + o_tki);
    float* tkw    = (float*)(w + o_tkw);
    int*   etok   = (int*)(w + o_etok);
    float* ew     = (float*)(w + o_ew);
    int*   slotof = (int*)(w + o_slot);
    float* part   = (float*)(w + o_part);
    float* contrib= (float*)(w + o_ctb);

    const int rblocks = (ntok + TPB - 1) / TPB;
    hipLaunchKernelGGL(route_kernel, dim3(rblocks), dim3(BLOCK), 0, stream,
                       x, hasher_w, keys, tki, tkw, ntok);
    hipLaunchKernelGGL(scanfill_kernel, dim3(1), dim3(NPAT), 0, stream,
                       tki, tkw, scale, offs, etok, ew, slotof, nent);
    hipLaunchKernelGGL(proj_kernel, dim3(NPAT * NCH), dim3(BLOCK), 0, stream,
                       x, vd, offs, etok, part, nent);

    if (ws_size >= needContrib) {
        hipLaunchKernelGGL((up_kernel<0>), dim3(NPAT * NCH), dim3(BLOCK), 0, stream,
                           vu, offs, etok, ew, part, contrib, nent);
        hipLaunchKernelGGL(combine_kernel, dim3(ntok), dim3(BLOCK), 0, stream,
                           x, contrib, slotof, out);
    } else if (ws_size >= needPart) {
        hipMemcpyAsync(out, x, (size_t)ntok * DDIM * 4, hipMemcpyDeviceToDevice,
                       stream);
        hipLaunchKernelGGL((up_kernel<1>), dim3(NPAT * NCH), dim3(BLOCK), 0, stream,
                           vu, offs, etok, ew, part, out, nent);
    }
}

// Round 8
// 238.004 us; speedup vs baseline: 3.5605x; 1.2523x over previous
//
#include <hip/hip_runtime.h>
#include <math.h>
#include <float.h>

#define DDIM 1024   // D
#define PDIM 32     // pattern_dim
#define NPAT 256    // n_patterns
#define TOPK 4
#define BLOCK 256
#define GT   16     // tokens per tile
#define DCH  256    // d-chunk per block
#define NCH  4      // d-chunks (DDIM/DCH)
#define RTPB 4      // tokens per route block (one per wave)

// ---------------------------------------------------------------------------
// K0 (R8): routing, one WAVE per token, 4 tokens/block, 512 blocks.
// Lane l holds x[tok][d] for d in {i*256 + l*4 ..+3, i=0..3} (16 floats) and
// accumulates partial h for ALL 32 pattern-dims in registers. Transpose-
// reduce via LDS P[l][pp] (row pad 33 -> banks (l+pp)%32, 2-way max = free).
// Then in-wave sim vs 256 keys + top-4 butterfly argmax (tie -> lower index)
// + softmax (logic verbatim from R7 phase 2, which validated).
__global__ __launch_bounds__(BLOCK) void route_kernel(
    const float* __restrict__ x,
    const float* __restrict__ hasher_w,   // [PDIM, DDIM]
    const float* __restrict__ keys,       // [NPAT, PDIM]
    int*   __restrict__ tki,              // [ntok, TOPK]
    float* __restrict__ tkw,              // [ntok, TOPK]
    int ntok)
{
    __shared__ float P_s[RTPB][64 * 33];  // 33.8 KB transpose scratch
    __shared__ float h_s[RTPB][32];

    const int tid  = threadIdx.x;
    const int wv   = tid >> 6;            // wave 0..3 = local token
    const int lane = tid & 63;
    const int tok  = min(blockIdx.x * RTPB + wv, ntok - 1);  // clamp (dup-write benign)

    // ---- x row into registers (coalesced float4)
    const float4* xrow = (const float4*)(x + (size_t)tok * DDIM);
    float4 xr[4];
    #pragma unroll
    for (int i = 0; i < 4; ++i) xr[i] = xrow[i * 64 + lane];

    // ---- per-lane partial h[pp] over this lane's 16 d's
    float part[PDIM];
    #pragma unroll
    for (int pp = 0; pp < PDIM; ++pp) {
        const float4* wrow = (const float4*)(hasher_w + (size_t)pp * DDIM);
        float a = 0.f;
        #pragma unroll
        for (int i = 0; i < 4; ++i) {
            const float4 w4 = wrow[i * 64 + lane];
            a = fmaf(xr[i].x, w4.x, a); a = fmaf(xr[i].y, w4.y, a);
            a = fmaf(xr[i].z, w4.z, a); a = fmaf(xr[i].w, w4.w, a);
        }
        part[pp] = a;
    }

    // ---- transpose-reduce: P[l][pp] -> h[pp]
    float* P = P_s[wv];
    #pragma unroll
    for (int pp = 0; pp < PDIM; ++pp) P[lane * 33 + pp] = part[pp];
    __syncthreads();

    {
        const int pp = lane & 31, half = lane >> 5;
        float hsum = 0.f;
        #pragma unroll 8
        for (int i = 0; i < 32; ++i)
            hsum += P[(half * 32 + i) * 33 + pp];
        hsum += __shfl_xor(hsum, 32, 64);
        if (half == 0) h_s[wv][pp] = hsum;
    }
    __syncthreads();

    // ---- sim + top4 + softmax (in-wave; verbatim logic from R7 phase 2)
    float4 h4[8];
    #pragma unroll
    for (int i = 0; i < 8; ++i) h4[i] = *(const float4*)&h_s[wv][i * 4];

    float sc0, sc1, sc2, sc3;
    {
        float sv[4];
        #pragma unroll
        for (int c = 0; c < 4; ++c) {
            const float4* kr = (const float4*)(keys + (size_t)(c * 64 + lane) * PDIM);
            float a = 0.f;
            #pragma unroll
            for (int i = 0; i < 8; ++i) {
                const float4 k4 = kr[i];
                a = fmaf(k4.x, h4[i].x, a); a = fmaf(k4.y, h4[i].y, a);
                a = fmaf(k4.z, h4[i].z, a); a = fmaf(k4.w, h4[i].w, a);
            }
            sv[c] = a;
        }
        sc0 = sv[0]; sc1 = sv[1]; sc2 = sv[2]; sc3 = sv[3];
    }

    float wval[TOPK]; int widx[TOPK];
    #pragma unroll
    for (int r = 0; r < TOPK; ++r) {
        float bv = sc0; int bc = 0;
        if (sc1 > bv) { bv = sc1; bc = 1; }
        if (sc2 > bv) { bv = sc2; bc = 2; }
        if (sc3 > bv) { bv = sc3; bc = 3; }
        int bidx = bc * 64 + lane;
        #pragma unroll
        for (int off = 1; off < 64; off <<= 1) {
            const float ov = __shfl_xor(bv, off, 64);
            const int   oi = __shfl_xor(bidx, off, 64);
            if (ov > bv || (ov == bv && oi < bidx)) { bv = ov; bidx = oi; }
        }
        wval[r] = bv; widx[r] = bidx;
        if ((bidx & 63) == lane) {
            const int c = bidx >> 6;
            if (c == 0) sc0 = -FLT_MAX;
            else if (c == 1) sc1 = -FLT_MAX;
            else if (c == 2) sc2 = -FLT_MAX;
            else sc3 = -FLT_MAX;
        }
    }

    if (lane == 0) {
        float m = wval[0];
        #pragma unroll
        for (int k = 1; k < TOPK; ++k) m = fmaxf(m, wval[k]);
        float s = 0.f, e[TOPK];
        #pragma unroll
        for (int k = 0; k < TOPK; ++k) { e[k] = expf(wval[k] - m); s += e[k]; }
        #pragma unroll
        for (int k = 0; k < TOPK; ++k) {
            tki[tok * TOPK + k] = widx[k];
            tkw[tok * TOPK + k] = e[k] / s;
        }
    }
}

// ---------------------------------------------------------------------------
// K1: count (from tki, in LDS) + scan + CSR fill, single block (R7-verified).
__global__ __launch_bounds__(NPAT) void scanfill_kernel(
    const int* __restrict__ tki, const float* __restrict__ tkw,
    const float* __restrict__ scale_p,
    int* __restrict__ offs,
    int* __restrict__ etok, float* __restrict__ ew, int* __restrict__ slotof,
    int nent)
{
    __shared__ int s[NPAT];
    __shared__ int cur[NPAT];
    const int tid = threadIdx.x;

    cur[tid] = 0;
    __syncthreads();
    for (int e = tid; e < nent; e += NPAT) atomicAdd(&cur[tki[e]], 1);
    __syncthreads();

    const int v = cur[tid];
    s[tid] = v;
    __syncthreads();
    for (int off = 1; off < NPAT; off <<= 1) {
        int t = 0;
        if (tid >= off) t = s[tid - off];
        __syncthreads();
        s[tid] += t;
        __syncthreads();
    }
    const int incl = s[tid];
    offs[tid + 1] = incl;
    if (tid == 0) offs[0] = 0;
    cur[tid] = incl - v;
    __syncthreads();

    const float sc = scale_p[0];
    for (int e = tid; e < nent; e += NPAT) {
        const int p = tki[e];
        const int slot = atomicAdd(&cur[p], 1);
        etok[slot] = e >> 2;
        ew[slot]   = tkw[e] * sc;
        slotof[e]  = slot;
    }
}

// ---------------------------------------------------------------------------
// K2: down-projection, d-split (verbatim from R4's 248 µs best).
__global__ __launch_bounds__(BLOCK, 2) void proj_kernel(
    const float* __restrict__ x,
    const float* __restrict__ vd,          // [NPAT, DDIM, PDIM]
    const int* __restrict__ offs,
    const int* __restrict__ etok,
    float* __restrict__ part,              // [NCH][nent+1][PDIM]
    int nent)
{
    __shared__ float vd_s[DCH * PDIM];     // 32 KB
    __shared__ float x_s[GT * DCH];        // 16 KB
    __shared__ float red[4][8][68];        // 8.7 KB
    __shared__ int   gt[GT];
    __shared__ int   gs[GT];

    const int p   = blockIdx.x >> 2;
    const int c   = blockIdx.x & 3;
    const int tid = threadIdx.x;
    const int off0 = offs[p];
    const int n    = offs[p + 1] - off0;
    if (n == 0) return;

    const float* vdp = vd + (size_t)p * DDIM * PDIM + (size_t)c * DCH * PDIM;
    #pragma unroll
    for (int k = 0; k < 8; ++k)
        ((float4*)vd_s)[k * 256 + tid] = ((const float4*)vdp)[k * 256 + tid];
    __syncthreads();

    const int pp4 = tid & 7;
    const int seg = tid >> 3;
    float* partc = part + (size_t)c * (size_t)(nent + 1) * PDIM;

    for (int t0 = 0; t0 < n; t0 += GT) {
        const int gv = min(GT, n - t0);
        if (tid < GT) {
            if (tid < gv) { gt[tid] = etok[off0 + t0 + tid]; gs[tid] = off0 + t0 + tid; }
            else          { gt[tid] = etok[off0];            gs[tid] = nent; }
        }
        __syncthreads();

        #pragma unroll
        for (int k = 0; k < 4; ++k) {
            const int q  = k * 256 + tid;
            const int g  = q >> 6, fi = q & 63;
            ((float4*)x_s)[g * 64 + fi] =
                *(const float4*)(x + (size_t)gt[g] * DDIM + c * DCH + fi * 4);
        }
        __syncthreads();

        float4 acc[GT];
        #pragma unroll
        for (int g = 0; g < GT; ++g) acc[g] = make_float4(0.f, 0.f, 0.f, 0.f);

        #pragma unroll
        for (int i4 = 0; i4 < 2; ++i4) {
            const int d0 = seg * 8 + i4 * 4;
            const float4 v0 = *(const float4*)&vd_s[(d0 + 0) * PDIM + pp4 * 4];
            const float4 v1 = *(const float4*)&vd_s[(d0 + 1) * PDIM + pp4 * 4];
            const float4 v2 = *(const float4*)&vd_s[(d0 + 2) * PDIM + pp4 * 4];
            const float4 v3 = *(const float4*)&vd_s[(d0 + 3) * PDIM + pp4 * 4];
            #pragma unroll
            for (int g = 0; g < GT; ++g) {
                const float4 xg = *(const float4*)&x_s[g * DCH + d0];
                acc[g].x = fmaf(xg.x, v0.x, acc[g].x);
                acc[g].y = fmaf(xg.x, v0.y, acc[g].y);
                acc[g].z = fmaf(xg.x, v0.z, acc[g].z);
                acc[g].w = fmaf(xg.x, v0.w, acc[g].w);
                acc[g].x = fmaf(xg.y, v1.x, acc[g].x);
                acc[g].y = fmaf(xg.y, v1.y, acc[g].y);
                acc[g].z = fmaf(xg.y, v1.z, acc[g].z);
                acc[g].w = fmaf(xg.y, v1.w, acc[g].w);
                acc[g].x = fmaf(xg.z, v2.x, acc[g].x);
                acc[g].y = fmaf(xg.z, v2.y, acc[g].y);
                acc[g].z = fmaf(xg.z, v2.z, acc[g].z);
                acc[g].w = fmaf(xg.z, v2.w, acc[g].w);
                acc[g].x = fmaf(xg.w, v3.x, acc[g].x);
                acc[g].y = fmaf(xg.w, v3.y, acc[g].y);
                acc[g].z = fmaf(xg.w, v3.z, acc[g].z);
                acc[g].w = fmaf(xg.w, v3.w, acc[g].w);
            }
        }

        #pragma unroll
        for (int g = 0; g < GT; ++g) {
            #pragma unroll
            for (int off = 8; off <= 32; off <<= 1) {
                acc[g].x += __shfl_xor(acc[g].x, off, 64);
                acc[g].y += __shfl_xor(acc[g].y, off, 64);
                acc[g].z += __shfl_xor(acc[g].z, off, 64);
                acc[g].w += __shfl_xor(acc[g].w, off, 64);
            }
        }
        const int wv = tid >> 6;
        if ((tid & 0x38) == 0) {
            #pragma unroll
            for (int g = 0; g < GT; ++g)
                *(float4*)&red[wv][pp4][g * 4] = acc[g];
        }
        __syncthreads();

        #pragma unroll
        for (int r = 0; r < 2; ++r) {
            const int idx = tid + r * BLOCK;
            const int g = idx >> 5, pp = idx & 31;
            const int q = pp >> 2, cmp = g * 4 + (pp & 3);
            const float s = red[0][q][cmp] + red[1][q][cmp]
                          + red[2][q][cmp] + red[3][q][cmp];
            partc[(size_t)gs[g] * PDIM + pp] = s;
        }
        __syncthreads();
    }
}

// ---------------------------------------------------------------------------
// K3: up-projection, d-split (verbatim from R4's 248 µs best).
template <int MODE>
__global__ __launch_bounds__(BLOCK, 4) void up_kernel(
    const float* __restrict__ vu,          // [NPAT, PDIM, DDIM]
    const int* __restrict__ offs,
    const int* __restrict__ etok,
    const float* __restrict__ ew,
    const float* __restrict__ part,        // [NCH][nent+1][PDIM]
    float* __restrict__ dst,               // contrib (MODE 0) or out (MODE 1)
    int nent)
{
    __shared__ float vu_s[PDIM * DCH];     // 32 KB
    __shared__ float projT[PDIM][20];
    __shared__ int   gt[GT];
    __shared__ float gw[GT];
    __shared__ int   gs[GT];

    const int p   = blockIdx.x >> 2;
    const int c   = blockIdx.x & 3;
    const int tid = threadIdx.x;
    const int off0 = offs[p];
    const int n    = offs[p + 1] - off0;
    if (n == 0) return;

    const size_t PS = (size_t)(nent + 1) * PDIM;

    const float* vup = vu + (size_t)p * PDIM * DDIM + (size_t)c * DCH;
    #pragma unroll
    for (int k = 0; k < 8; ++k) {
        const int q  = k * 256 + tid;
        const int pp = q >> 6, fi = q & 63;
        *(float4*)&vu_s[pp * DCH + fi * 4] =
            *(const float4*)(vup + (size_t)pp * DDIM + fi * 4);
    }
    __syncthreads();

    const int gq   = tid >> 6;
    const int lane = tid & 63;

    for (int t0 = 0; t0 < n; t0 += GT) {
        const int gv = min(GT, n - t0);
        if (tid < GT) {
            if (tid < gv) {
                gt[tid] = etok[off0 + t0 + tid];
                gw[tid] = ew[off0 + t0 + tid];
                gs[tid] = off0 + t0 + tid;
            } else {
                gt[tid] = etok[off0]; gw[tid] = 0.f; gs[tid] = nent;
            }
        }
        __syncthreads();

        #pragma unroll
        for (int r = 0; r < 2; ++r) {
            const int idx = tid + r * BLOCK;
            const int g = idx >> 5, pp = idx & 31;
            const size_t row = (size_t)gs[g] * PDIM + pp;
            const float s = part[row] + part[PS + row]
                          + part[2 * PS + row] + part[3 * PS + row];
            const float pj = s / (1.f + expf(-s));
            projT[pp][g] = pj * gw[g];
        }
        __syncthreads();

        float4 o0 = make_float4(0.f, 0.f, 0.f, 0.f);
        float4 o1 = o0, o2 = o0, o3 = o0;
        #pragma unroll
        for (int pp = 0; pp < PDIM; ++pp) {
            const float4 pj4 = *(const float4*)&projT[pp][gq * 4];
            const float4 vu4 = *(const float4*)&vu_s[pp * DCH + lane * 4];
            o0.x = fmaf(pj4.x, vu4.x, o0.x); o0.y = fmaf(pj4.x, vu4.y, o0.y);
            o0.z = fmaf(pj4.x, vu4.z, o0.z); o0.w = fmaf(pj4.x, vu4.w, o0.w);
            o1.x = fmaf(pj4.y, vu4.x, o1.x); o1.y = fmaf(pj4.y, vu4.y, o1.y);
            o1.z = fmaf(pj4.y, vu4.z, o1.z); o1.w = fmaf(pj4.y, vu4.w, o1.w);
            o2.x = fmaf(pj4.z, vu4.x, o2.x); o2.y = fmaf(pj4.z, vu4.y, o2.y);
            o2.z = fmaf(pj4.z, vu4.z, o2.z); o2.w = fmaf(pj4.z, vu4.w, o2.w);
            o3.x = fmaf(pj4.w, vu4.x, o3.x); o3.y = fmaf(pj4.w, vu4.y, o3.y);
            o3.z = fmaf(pj4.w, vu4.z, o3.z); o3.w = fmaf(pj4.w, vu4.w, o3.w);
        }

        float4 ov[4] = {o0, o1, o2, o3};
        if (MODE == 0) {
            #pragma unroll
            for (int j = 0; j < 4; ++j)
                *(float4*)(dst + (size_t)gs[gq * 4 + j] * DDIM + c * DCH + lane * 4) = ov[j];
        } else {
            #pragma unroll
            for (int j = 0; j < 4; ++j) {
                const int g = gq * 4 + j;
                if (g < gv) {
                    float* op = dst + (size_t)gt[g] * DDIM + c * DCH + lane * 4;
                    atomicAdd(op + 0, ov[j].x);
                    atomicAdd(op + 1, ov[j].y);
                    atomicAdd(op + 2, ov[j].z);
                    atomicAdd(op + 3, ov[j].w);
                }
            }
        }
        __syncthreads();
    }
}

// ---------------------------------------------------------------------------
// K4: out[t] = x[t] + sum_k contrib[slotof[t][k]]  (verbatim-verified)
__global__ __launch_bounds__(BLOCK) void combine_kernel(
    const float* __restrict__ x, const float* __restrict__ contrib,
    const int* __restrict__ slotof, float* __restrict__ out)
{
    __shared__ int sl[TOPK];
    const int t = blockIdx.x, tid = threadIdx.x;
    if (tid < TOPK) sl[tid] = slotof[t * TOPK + tid];
    __syncthreads();
    float4 r = ((const float4*)(x + (size_t)t * DDIM))[tid];
    #pragma unroll
    for (int k = 0; k < TOPK; ++k) {
        const float4 cv = ((const float4*)(contrib + (size_t)sl[k] * DDIM))[tid];
        r.x += cv.x; r.y += cv.y; r.z += cv.z; r.w += cv.w;
    }
    ((float4*)(out + (size_t)t * DDIM))[tid] = r;
}

// ---------------------------------------------------------------------------
extern "C" void kernel_launch(void* const* d_in, const int* in_sizes, int n_in,
                              void* d_out, int out_size, void* d_ws, size_t ws_size,
                              hipStream_t stream) {
    const float* x        = (const float*)d_in[0];
    const float* hasher_w = (const float*)d_in[1];
    const float* keys     = (const float*)d_in[2];
    const float* vd       = (const float*)d_in[3];
    const float* vu       = (const float*)d_in[4];
    const float* scale    = (const float*)d_in[5];
    float* out = (float*)d_out;

    const int ntok = in_sizes[0] / DDIM;        // B*T
    const int nent = ntok * TOPK;

    // workspace layout
    char* w = (char*)d_ws;
    const size_t o_offs = 1024;                                   // 257 int
    const size_t o_tki  = 2560;                                   // nent int
    const size_t o_tkw  = o_tki  + (size_t)nent * 4;
    const size_t o_etok = o_tkw  + (size_t)nent * 4;
    const size_t o_ew   = o_etok + (size_t)nent * 4;
    const size_t o_slot = o_ew   + (size_t)nent * 4;
    const size_t o_part = (o_slot + (size_t)nent * 4 + 255) & ~(size_t)255;
    const size_t partsz = (size_t)NCH * (size_t)(nent + 1) * PDIM * 4;
    const size_t o_ctb  = (o_part + partsz + 255) & ~(size_t)255;
    const size_t needPart    = o_ctb;                              // atomic path
    const size_t needContrib = o_ctb + (size_t)(nent + 1) * DDIM * 4;

    int*   offs   = (int*)(w + o_offs);
    int*   tki    = (int*)(w + o_tki);
    float* tkw    = (float*)(w + o_tkw);
    int*   etok   = (int*)(w + o_etok);
    float* ew     = (float*)(w + o_ew);
    int*   slotof = (int*)(w + o_slot);
    float* part   = (float*)(w + o_part);
    float* contrib= (float*)(w + o_ctb);

    const int rblocks = (ntok + RTPB - 1) / RTPB;
    hipLaunchKernelGGL(route_kernel, dim3(rblocks), dim3(BLOCK), 0, stream,
                       x, hasher_w, keys, tki, tkw, ntok);
    hipLaunchKernelGGL(scanfill_kernel, dim3(1), dim3(NPAT), 0, stream,
                       tki, tkw, scale, offs, etok, ew, slotof, nent);
    hipLaunchKernelGGL(proj_kernel, dim3(NPAT * NCH), dim3(BLOCK), 0, stream,
                       x, vd, offs, etok, part, nent);

    if (ws_size >= needContrib) {
        hipLaunchKernelGGL((up_kernel<0>), dim3(NPAT * NCH), dim3(BLOCK), 0, stream,
                           vu, offs, etok, ew, part, contrib, nent);
        hipLaunchKernelGGL(combine_kernel, dim3(ntok), dim3(BLOCK), 0, stream,
                           x, contrib, slotof, out);
    } else if (ws_size >= needPart) {
        hipMemcpyAsync(out, x, (size_t)ntok * DDIM * 4, hipMemcpyDeviceToDevice,
                       stream);
        hipLaunchKernelGGL((up_kernel<1>), dim3(NPAT * NCH), dim3(BLOCK), 0, stream,
                           vu, offs, etok, ew, part, out, nent);
    }
}